// Round 10
// baseline (76.223 us; speedup 1.0000x reference)
//
#include <hip/hip_runtime.h>
#include <hip/hip_bf16.h>
#include <cstdint>

#define B_ 8
#define C_ 128
#define N_ 16384   // H*W
#define CHN 512    // n per KA block
#define SN 128     // n per KA subtile
#define NST 4      // subtiles per KA block
#define NC (N_ / CHN)  // 32 chunks
#define SN4 64     // n per K4 block

typedef __attribute__((ext_vector_type(8))) short short8;
typedef __attribute__((ext_vector_type(4))) float f32x4;
typedef __attribute__((ext_vector_type(4))) unsigned short us4;
typedef unsigned short u16;

__device__ __forceinline__ short f2bf(float f) {
  union { float f; unsigned u; } c; c.f = f;
  unsigned r = (c.u + 0x7FFFu + ((c.u >> 16) & 1u)) >> 16;
  return (short)r;
}

__device__ __forceinline__ unsigned cvtpk(float lo, float hi) {
  unsigned r;
  asm("v_cvt_pk_bf16_f32 %0, %1, %2" : "=v"(r) : "v"(lo), "v"(hi));
  return r;
}

union SB { short8 s8; unsigned u[4]; };

// ---------------------------------------------------------------------------
// K0: preconvert k_w, v_w (fp32) -> wbf (bf16 [2][128][128])
// ---------------------------------------------------------------------------
__global__ __launch_bounds__(256) void k0_wcvt(const float* __restrict__ kw,
                                               const float* __restrict__ vw,
                                               u16* __restrict__ wbf) {
  const int g = blockIdx.x * 256 + threadIdx.x;  // 0..8191 float4s
  const int mat = g >> 12, o4 = g & 4095;
  const float* src = mat ? vw : kw;
  float4 f = reinterpret_cast<const float4*>(src)[o4];
  us4 s;
  s[0] = (u16)f2bf(f.x); s[1] = (u16)f2bf(f.y);
  s[2] = (u16)f2bf(f.z); s[3] = (u16)f2bf(f.w);
  reinterpret_cast<us4*>(wbf + (size_t)mat * C_ * C_)[o4] = s;
}

// ---------------------------------------------------------------------------
// KA: fused projection + context partial (unchanged from rounds 6/8/9;
// passed with absmax 0.03125).
// ---------------------------------------------------------------------------
#define KA_LOADS(ST_) do {                                                   \
  _Pragma("unroll") for (int h_ = 0; h_ < 2; ++h_)                           \
  _Pragma("unroll") for (int j_ = 0; j_ < 16; ++j_)                          \
    xr[h_][j_] = xw[(size_t)j_ * N_ + (ST_) * SN + h_ * 64 + lane];          \
} while (0)

#define KA_XWRITE(BUF_) do {                                                 \
  _Pragma("unroll") for (int h_ = 0; h_ < 2; ++h_) {                         \
    const int n_ = h_ * 64 + lane;                                           \
    unsigned pk_[8];                                                         \
    _Pragma("unroll") for (int p_ = 0; p_ < 8; ++p_)                         \
      pk_[p_] = cvtpk(xr[h_][2 * p_], xr[h_][2 * p_ + 1]);                   \
    _Pragma("unroll") for (int o_ = 0; o_ < 2; ++o_) {                       \
      uint4 q_;                                                              \
      q_.x = pk_[o_ * 4]; q_.y = pk_[o_ * 4 + 1];                            \
      q_.z = pk_[o_ * 4 + 2]; q_.w = pk_[o_ * 4 + 3];                        \
      *reinterpret_cast<uint4*>(                                             \
          (BUF_) + n_ * SN + ((w * 16 + o_ * 8) ^ ((n_ & 7) << 3))) = q_;    \
    }                                                                        \
  }                                                                          \
} while (0)

__global__ __launch_bounds__(512, 2) void ka_projctx(
    const float* __restrict__ kv, const u16* __restrict__ wbf,
    const float* __restrict__ kb, const float* __restrict__ vb,
    float* __restrict__ part, float* __restrict__ zpart) {
  __shared__ u16 xt[2][C_ * SN];   // 2 x 32 KB transposed bf16 x
  __shared__ u16 eks[C_ * SN];     // 32 KB EK stash [d][n]
  __shared__ u16 vs [C_ * SN];     // 32 KB V  stash [c][n]

  const int b = blockIdx.y, kc = blockIdx.x;
  const int tid = threadIdx.x;
  const int w = tid >> 6, lane = tid & 63;
  const int lg = lane >> 4, li = lane & 15;
  const int mat = w >> 2, dblk = w & 3;
  const int cg = w >> 1, dh = w & 1;

  const float* xb = kv + (size_t)b * C_ * N_ + (size_t)kc * CHN;
  const float* xw = xb + (size_t)(w * 16) * N_;  // wave's 16 c-rows
  const u16* Wm = wbf + (size_t)mat * C_ * C_;
  const float* biasp = mat ? vb : kb;
  u16* S = mat ? vs : eks;

  short8 wreg[2][4];
#pragma unroll
  for (int dt = 0; dt < 2; ++dt)
#pragma unroll
    for (int ks = 0; ks < 4; ++ks)
      wreg[dt][ks] = *reinterpret_cast<const short8*>(
          Wm + (dblk * 32 + dt * 16 + li) * C_ + ks * 32 + lg * 8);
  float bias2[2];
#pragma unroll
  for (int dt = 0; dt < 2; ++dt) bias2[dt] = biasp[dblk * 32 + dt * 16 + li];

  f32x4 acc[2][4] = {};   // ctx accumulator [am c][dt d]
  float zac[2] = {0.f, 0.f};
  float xr[2][16];        // reg-staged x: [n-half][c-row j]

  KA_LOADS(0);
  KA_XWRITE(&xt[0][0]);
  KA_LOADS(1);
  asm volatile("s_waitcnt lgkmcnt(0)" ::: "memory");
  __builtin_amdgcn_s_barrier();
  __builtin_amdgcn_sched_barrier(0);

#pragma unroll
  for (int st = 0; st < NST; ++st) {
    const u16* xc = &xt[st & 1][0];

    if (st < NST - 1) {
      KA_XWRITE(&xt[(st + 1) & 1][0]);
      if (st < NST - 2) KA_LOADS(st + 2);
    }

    // ---- proj: D[n][d] = xT · W^T, in nt-pairs ----
#pragma unroll
    for (int h2 = 0; h2 < 4; ++h2) {
      f32x4 pacc[2][2] = {};  // [ntl][dt]
#pragma unroll
      for (int ntl = 0; ntl < 2; ++ntl) {
        const int n = (h2 * 2 + ntl) * 16 + li;
#pragma unroll
        for (int ks = 0; ks < 4; ++ks) {
          short8 a = *reinterpret_cast<const short8*>(
              xc + n * SN + ((ks * 32 + lg * 8) ^ ((n & 7) << 3)));
#pragma unroll
          for (int dt = 0; dt < 2; ++dt)
            pacc[ntl][dt] = __builtin_amdgcn_mfma_f32_16x16x32_bf16(
                a, wreg[dt][ks], pacc[ntl][dt], 0, 0, 0);
        }
      }
#pragma unroll
      for (int dt = 0; dt < 2; ++dt) {
        const int d = dblk * 32 + dt * 16 + li;
        const float bias = bias2[dt];
#pragma unroll
        for (int ntl = 0; ntl < 2; ++ntl) {
          float v0 = pacc[ntl][dt][0] + bias;
          float v1 = pacc[ntl][dt][1] + bias;
          float v2 = pacc[ntl][dt][2] + bias;
          float v3 = pacc[ntl][dt][3] + bias;
          if (mat == 0) {
            v0 = __expf(v0); v1 = __expf(v1); v2 = __expf(v2); v3 = __expf(v3);
            zac[dt] += (v0 + v1) + (v2 + v3);
          }
          const int nq = (h2 * 2 + ntl) * 16 + lg * 4;
          uint2 pk; pk.x = cvtpk(v0, v1); pk.y = cvtpk(v2, v3);
          *reinterpret_cast<uint2*>(S + d * SN + (nq ^ ((d & 7) << 3))) = pk;
        }
      }
    }
    asm volatile("s_waitcnt lgkmcnt(0)" ::: "memory");
    __builtin_amdgcn_s_barrier();
    __builtin_amdgcn_sched_barrier(0);

    // ---- ctx: part += V·EK^T over this subtile's 128 n ----
#pragma unroll
    for (int kk = 0; kk < 4; ++kk) {
      const int n0 = kk * 32 + lg * 8;
      short8 a[2], bb[4];
#pragma unroll
      for (int am = 0; am < 2; ++am) {
        const int c = cg * 32 + am * 16 + li;
        a[am] = *reinterpret_cast<const short8*>(vs + c * SN + (n0 ^ ((c & 7) << 3)));
      }
#pragma unroll
      for (int dt = 0; dt < 4; ++dt) {
        const int d = dh * 64 + dt * 16 + li;
        bb[dt] = *reinterpret_cast<const short8*>(eks + d * SN + (n0 ^ ((d & 7) << 3)));
      }
#pragma unroll
      for (int am = 0; am < 2; ++am)
#pragma unroll
        for (int dt = 0; dt < 4; ++dt)
          acc[am][dt] = __builtin_amdgcn_mfma_f32_16x16x32_bf16(a[am], bb[dt], acc[am][dt], 0, 0, 0);
    }
    asm volatile("s_waitcnt lgkmcnt(0)" ::: "memory");
    __builtin_amdgcn_s_barrier();
    __builtin_amdgcn_sched_barrier(0);
  }

  // ---- epilogue: part + zpart (deterministic, no atomics) ----
  float* P = part + ((size_t)kc * B_ + b) * C_ * C_;
#pragma unroll
  for (int am = 0; am < 2; ++am)
#pragma unroll
    for (int dt = 0; dt < 4; ++dt)
#pragma unroll
      for (int r = 0; r < 4; ++r) {
        const int c = cg * 32 + am * 16 + lg * 4 + r;
        const int d = dh * 64 + dt * 16 + li;
        P[c * C_ + d] = acc[am][dt][r];
      }
  if (mat == 0) {
#pragma unroll
    for (int dt = 0; dt < 2; ++dt) {
      float z = zac[dt];
      z += __shfl_xor(z, 16);
      z += __shfl_xor(z, 32);
      if (lg == 0)
        zpart[((size_t)kc * B_ + b) * C_ + dblk * 32 + dt * 16 + li] = z;
    }
  }
}

// ---------------------------------------------------------------------------
// KB2: cs = (sum_kc part)/Z ; M = cs·qw (bf16), T = cs·qb
// (unchanged from rounds 8/9)
// ---------------------------------------------------------------------------
__global__ __launch_bounds__(256) void kb2_fin(
    const float* __restrict__ part, const float* __restrict__ zpart,
    const float* __restrict__ qw, const float* __restrict__ qb,
    u16* __restrict__ M, float* __restrict__ T) {
  const int b = blockIdx.y;
  const int cs0 = blockIdx.x * 16;
  const int tid = threadIdx.x;
  __shared__ float cs[16][128];
  __shared__ float Zs[128];
  if (tid < 128) {
    float s = 0.f;
    for (int kc = 0; kc < NC; ++kc)
      s += zpart[((size_t)kc * B_ + b) * C_ + tid];
    Zs[tid] = s;
  }
  __syncthreads();
#pragma unroll
  for (int i = 0; i < 8; ++i) {
    const int e = tid + i * 256;
    const int cl = e >> 7, d = e & 127;
    float s = 0.f;
    for (int kc = 0; kc < NC; ++kc)
      s += part[(((size_t)kc * B_ + b) * C_ + (cs0 + cl)) * C_ + d];
    cs[cl][d] = s / Zs[d];
  }
  __syncthreads();
  const int cl = tid >> 4, e0 = (tid & 15) * 8;
  float m[8] = {};
  for (int d = 0; d < 128; ++d) {
    const float cv = cs[cl][d];
    const float* qr = qw + d * C_ + e0;
#pragma unroll
    for (int j = 0; j < 8; ++j) m[j] += cv * qr[j];
  }
  u16* mp = M + ((size_t)b * C_ + cs0 + cl) * C_ + e0;
#pragma unroll
  for (int j = 0; j < 8; ++j) mp[j] = (u16)f2bf(m[j]);
  if (tid < 16) {
    float tv = 0.f;
    for (int d = 0; d < 128; ++d) tv += cs[tid][d] * qb[d];
    T[b * C_ + cs0 + tid] = tv;
  }
}

// ---------------------------------------------------------------------------
// K4: out = M·q_feat + T (fp32).  grid (N/64, B), 256 thr = 4 waves.
// Round-9 staging/MFMA + NEW LDS-transpose epilogue:
//   phase A: q->regs (coalesced), cvtpk, ds_write qt[n][d] bf16 (16 KB)
//   phase B: barrier; MFMA D[c][n] from qt
//   phase C: barrier; acc(+T) -> ostage[c][n] fp32 (32 KB, overlays qt;
//            b32 writes XOR-swizzled, 2-way = free)
//   phase D: barrier; b128 row reads -> 256-B FULL-LINE global stores
//            (16 lanes x float4 per c-row; no partial-line RMW)
// Safety: every LDS phase transition is a __syncthreads() (r7's failure was
// same-wave ds ordering without a barrier).
// ---------------------------------------------------------------------------
__global__ __launch_bounds__(256) void k4_out(const u16* __restrict__ M,
                                              const float* __restrict__ T,
                                              const float* __restrict__ q,
                                              float* __restrict__ out) {
  __shared__ char lds[C_ * SN4 * 4];       // 32 KB
  u16*   qt     = (u16*)lds;               // [n][d] bf16 swizzled, 16 KB
  float* ostage = (float*)lds;             // [c][n] fp32 swizzled, 32 KB
  const int b = blockIdx.y;
  const int n0 = blockIdx.x * SN4;
  const int tid = threadIdx.x;
  const int w = tid >> 6, lane = tid & 63;
  const int lg = lane >> 4, li = lane & 15;

  // ---- phase A: stage q (wave w owns d-rows [w*32, w*32+32), lane = n) ----
  const float* qb = q + (size_t)b * C_ * N_ + n0;
  float xr[32];
#pragma unroll
  for (int j = 0; j < 32; ++j)
    xr[j] = qb[(size_t)(w * 32 + j) * N_ + lane];

  short8 mreg[2][4];
  const u16* Mb = M + (size_t)b * C_ * C_;
#pragma unroll
  for (int ct = 0; ct < 2; ++ct)
#pragma unroll
    for (int ks = 0; ks < 4; ++ks)
      mreg[ct][ks] = *reinterpret_cast<const short8*>(
          Mb + (w * 32 + ct * 16 + li) * C_ + ks * 32 + lg * 8);
  float tcv[2][4];
#pragma unroll
  for (int ct = 0; ct < 2; ++ct)
#pragma unroll
    for (int r = 0; r < 4; ++r)
      tcv[ct][r] = T[b * C_ + w * 32 + ct * 16 + lg * 4 + r];

#pragma unroll
  for (int o = 0; o < 4; ++o) {
    uint4 v;
    v.x = cvtpk(xr[o * 8 + 0], xr[o * 8 + 1]);
    v.y = cvtpk(xr[o * 8 + 2], xr[o * 8 + 3]);
    v.z = cvtpk(xr[o * 8 + 4], xr[o * 8 + 5]);
    v.w = cvtpk(xr[o * 8 + 6], xr[o * 8 + 7]);
    *reinterpret_cast<uint4*>(
        qt + lane * C_ + ((w * 32 + o * 8) ^ ((lane & 7) << 3))) = v;
  }
  __syncthreads();

  // ---- phase B: MFMA D[c][n]; c = lg*4+r, n = nt*16+li ----
  f32x4 acc[2][4] = {};  // [ct][nt]
#pragma unroll
  for (int nt = 0; nt < 4; ++nt) {
    const int n = nt * 16 + li;
#pragma unroll
    for (int ks = 0; ks < 4; ++ks) {
      short8 bb = *reinterpret_cast<const short8*>(
          qt + n * C_ + ((ks * 32 + lg * 8) ^ ((n & 7) << 3)));
#pragma unroll
      for (int ct = 0; ct < 2; ++ct)
        acc[ct][nt] = __builtin_amdgcn_mfma_f32_16x16x32_bf16(
            mreg[ct][ks], bb, acc[ct][nt], 0, 0, 0);
    }
  }
  __syncthreads();  // qt dead; ostage may overwrite

  // ---- phase C: acc(+T) -> ostage[c][n]  (b32 writes, 2-way banks) ----
#pragma unroll
  for (int ct = 0; ct < 2; ++ct)
#pragma unroll
    for (int nt = 0; nt < 4; ++nt)
#pragma unroll
      for (int r = 0; r < 4; ++r) {
        const int c = w * 32 + ct * 16 + lg * 4 + r;
        const int n = nt * 16 + li;
        ostage[c * SN4 + (n ^ ((c & 15) << 2))] = acc[ct][nt][r] + tcv[ct][r];
      }
  __syncthreads();

  // ---- phase D: row reads (b128) -> 256-B full-line stores ----
  const int rowg = lane >> 4, slot = lane & 15;
#pragma unroll
  for (int it = 0; it < 8; ++it) {
    const int c = it * 16 + w * 4 + rowg;
    float4 v = *reinterpret_cast<const float4*>(
        ostage + c * SN4 + ((slot * 4) ^ (((c & 15) << 2))));
    *reinterpret_cast<float4*>(
        out + ((size_t)b * C_ + c) * N_ + n0 + slot * 4) = v;
  }
}

// ---------------------------------------------------------------------------
extern "C" void kernel_launch(void* const* d_in, const int* in_sizes, int n_in,
                              void* d_out, int out_size, void* d_ws, size_t ws_size,
                              hipStream_t stream) {
  const float* q_feat  = (const float*)d_in[0];
  const float* kv_feat = (const float*)d_in[1];
  const float* q_w = (const float*)d_in[2];
  const float* q_b = (const float*)d_in[3];
  const float* k_w = (const float*)d_in[4];
  const float* k_b = (const float*)d_in[5];
  const float* v_w = (const float*)d_in[6];
  const float* v_b = (const float*)d_in[7];
  float* out = (float*)d_out;

  char* ws = (char*)d_ws;
  const size_t szPart = (size_t)NC * B_ * C_ * C_ * sizeof(float);  // 16 MB
  const size_t szZp   = (size_t)NC * B_ * C_ * sizeof(float);       // 128 KB
  const size_t szWbf  = (size_t)2 * C_ * C_ * sizeof(u16);          // 64 KB
  const size_t szM    = (size_t)B_ * C_ * C_ * sizeof(u16);         // 256 KB

  float* part  = (float*)ws;
  float* zpart = (float*)(ws + szPart);
  u16*   wbf   = (u16*)(ws + szPart + szZp);
  u16*   M     = (u16*)(ws + szPart + szZp + szWbf);
  float* T     = (float*)(ws + szPart + szZp + szWbf + szM);

  k0_wcvt<<<dim3(32), 256, 0, stream>>>(k_w, v_w, wbf);
  ka_projctx<<<dim3(NC, B_), 512, 0, stream>>>(kv_feat, wbf, k_b, v_b, part, zpart);
  kb2_fin<<<dim3(8, B_), 256, 0, stream>>>(part, zpart, q_w, q_b, M, T);
  k4_out<<<dim3(N_ / SN4, B_), 256, 0, stream>>>(M, T, q_feat, out);
}

// Round 11
// 75.728 us; speedup vs baseline: 1.0065x; 1.0065x over previous
//
#include <hip/hip_runtime.h>
#include <hip/hip_bf16.h>
#include <cstdint>

#define B_ 8
#define C_ 128
#define N_ 16384   // H*W
#define CHN 512    // n per KA block
#define SN 128     // n per KA subtile
#define NST 4      // subtiles per KA block
#define NC (N_ / CHN)  // 32 chunks
#define SN4 64     // n per K4 subtile

typedef __attribute__((ext_vector_type(8))) short short8;
typedef __attribute__((ext_vector_type(4))) float f32x4;
typedef __attribute__((ext_vector_type(4))) unsigned short us4;
typedef unsigned short u16;

__device__ __forceinline__ short f2bf(float f) {
  union { float f; unsigned u; } c; c.f = f;
  unsigned r = (c.u + 0x7FFFu + ((c.u >> 16) & 1u)) >> 16;
  return (short)r;
}

__device__ __forceinline__ unsigned cvtpk(float lo, float hi) {
  unsigned r;
  asm("v_cvt_pk_bf16_f32 %0, %1, %2" : "=v"(r) : "v"(lo), "v"(hi));
  return r;
}

union SB { short8 s8; unsigned u[4]; };

// ---------------------------------------------------------------------------
// K0: preconvert k_w, v_w (fp32) -> wbf (bf16 [2][128][128])
// ---------------------------------------------------------------------------
__global__ __launch_bounds__(256) void k0_wcvt(const float* __restrict__ kw,
                                               const float* __restrict__ vw,
                                               u16* __restrict__ wbf) {
  const int g = blockIdx.x * 256 + threadIdx.x;  // 0..8191 float4s
  const int mat = g >> 12, o4 = g & 4095;
  const float* src = mat ? vw : kw;
  float4 f = reinterpret_cast<const float4*>(src)[o4];
  us4 s;
  s[0] = (u16)f2bf(f.x); s[1] = (u16)f2bf(f.y);
  s[2] = (u16)f2bf(f.z); s[3] = (u16)f2bf(f.w);
  reinterpret_cast<us4*>(wbf + (size_t)mat * C_ * C_)[o4] = s;
}

// ---------------------------------------------------------------------------
// KA: fused projection + context partial (unchanged from rounds 6/8/9/10;
// passed with absmax 0.03125).
// ---------------------------------------------------------------------------
#define KA_LOADS(ST_) do {                                                   \
  _Pragma("unroll") for (int h_ = 0; h_ < 2; ++h_)                           \
  _Pragma("unroll") for (int j_ = 0; j_ < 16; ++j_)                          \
    xr[h_][j_] = xw[(size_t)j_ * N_ + (ST_) * SN + h_ * 64 + lane];          \
} while (0)

#define KA_XWRITE(BUF_) do {                                                 \
  _Pragma("unroll") for (int h_ = 0; h_ < 2; ++h_) {                         \
    const int n_ = h_ * 64 + lane;                                           \
    unsigned pk_[8];                                                         \
    _Pragma("unroll") for (int p_ = 0; p_ < 8; ++p_)                         \
      pk_[p_] = cvtpk(xr[h_][2 * p_], xr[h_][2 * p_ + 1]);                   \
    _Pragma("unroll") for (int o_ = 0; o_ < 2; ++o_) {                       \
      uint4 q_;                                                              \
      q_.x = pk_[o_ * 4]; q_.y = pk_[o_ * 4 + 1];                            \
      q_.z = pk_[o_ * 4 + 2]; q_.w = pk_[o_ * 4 + 3];                        \
      *reinterpret_cast<uint4*>(                                             \
          (BUF_) + n_ * SN + ((w * 16 + o_ * 8) ^ ((n_ & 7) << 3))) = q_;    \
    }                                                                        \
  }                                                                          \
} while (0)

__global__ __launch_bounds__(512, 2) void ka_projctx(
    const float* __restrict__ kv, const u16* __restrict__ wbf,
    const float* __restrict__ kb, const float* __restrict__ vb,
    float* __restrict__ part, float* __restrict__ zpart) {
  __shared__ u16 xt[2][C_ * SN];   // 2 x 32 KB transposed bf16 x
  __shared__ u16 eks[C_ * SN];     // 32 KB EK stash [d][n]
  __shared__ u16 vs [C_ * SN];     // 32 KB V  stash [c][n]

  const int b = blockIdx.y, kc = blockIdx.x;
  const int tid = threadIdx.x;
  const int w = tid >> 6, lane = tid & 63;
  const int lg = lane >> 4, li = lane & 15;
  const int mat = w >> 2, dblk = w & 3;
  const int cg = w >> 1, dh = w & 1;

  const float* xb = kv + (size_t)b * C_ * N_ + (size_t)kc * CHN;
  const float* xw = xb + (size_t)(w * 16) * N_;  // wave's 16 c-rows
  const u16* Wm = wbf + (size_t)mat * C_ * C_;
  const float* biasp = mat ? vb : kb;
  u16* S = mat ? vs : eks;

  short8 wreg[2][4];
#pragma unroll
  for (int dt = 0; dt < 2; ++dt)
#pragma unroll
    for (int ks = 0; ks < 4; ++ks)
      wreg[dt][ks] = *reinterpret_cast<const short8*>(
          Wm + (dblk * 32 + dt * 16 + li) * C_ + ks * 32 + lg * 8);
  float bias2[2];
#pragma unroll
  for (int dt = 0; dt < 2; ++dt) bias2[dt] = biasp[dblk * 32 + dt * 16 + li];

  f32x4 acc[2][4] = {};   // ctx accumulator [am c][dt d]
  float zac[2] = {0.f, 0.f};
  float xr[2][16];        // reg-staged x: [n-half][c-row j]

  KA_LOADS(0);
  KA_XWRITE(&xt[0][0]);
  KA_LOADS(1);
  asm volatile("s_waitcnt lgkmcnt(0)" ::: "memory");
  __builtin_amdgcn_s_barrier();
  __builtin_amdgcn_sched_barrier(0);

#pragma unroll
  for (int st = 0; st < NST; ++st) {
    const u16* xc = &xt[st & 1][0];

    if (st < NST - 1) {
      KA_XWRITE(&xt[(st + 1) & 1][0]);
      if (st < NST - 2) KA_LOADS(st + 2);
    }

    // ---- proj: D[n][d] = xT · W^T, in nt-pairs ----
#pragma unroll
    for (int h2 = 0; h2 < 4; ++h2) {
      f32x4 pacc[2][2] = {};  // [ntl][dt]
#pragma unroll
      for (int ntl = 0; ntl < 2; ++ntl) {
        const int n = (h2 * 2 + ntl) * 16 + li;
#pragma unroll
        for (int ks = 0; ks < 4; ++ks) {
          short8 a = *reinterpret_cast<const short8*>(
              xc + n * SN + ((ks * 32 + lg * 8) ^ ((n & 7) << 3)));
#pragma unroll
          for (int dt = 0; dt < 2; ++dt)
            pacc[ntl][dt] = __builtin_amdgcn_mfma_f32_16x16x32_bf16(
                a, wreg[dt][ks], pacc[ntl][dt], 0, 0, 0);
        }
      }
#pragma unroll
      for (int dt = 0; dt < 2; ++dt) {
        const int d = dblk * 32 + dt * 16 + li;
        const float bias = bias2[dt];
#pragma unroll
        for (int ntl = 0; ntl < 2; ++ntl) {
          float v0 = pacc[ntl][dt][0] + bias;
          float v1 = pacc[ntl][dt][1] + bias;
          float v2 = pacc[ntl][dt][2] + bias;
          float v3 = pacc[ntl][dt][3] + bias;
          if (mat == 0) {
            v0 = __expf(v0); v1 = __expf(v1); v2 = __expf(v2); v3 = __expf(v3);
            zac[dt] += (v0 + v1) + (v2 + v3);
          }
          const int nq = (h2 * 2 + ntl) * 16 + lg * 4;
          uint2 pk; pk.x = cvtpk(v0, v1); pk.y = cvtpk(v2, v3);
          *reinterpret_cast<uint2*>(S + d * SN + (nq ^ ((d & 7) << 3))) = pk;
        }
      }
    }
    asm volatile("s_waitcnt lgkmcnt(0)" ::: "memory");
    __builtin_amdgcn_s_barrier();
    __builtin_amdgcn_sched_barrier(0);

    // ---- ctx: part += V·EK^T over this subtile's 128 n ----
#pragma unroll
    for (int kk = 0; kk < 4; ++kk) {
      const int n0 = kk * 32 + lg * 8;
      short8 a[2], bb[4];
#pragma unroll
      for (int am = 0; am < 2; ++am) {
        const int c = cg * 32 + am * 16 + li;
        a[am] = *reinterpret_cast<const short8*>(vs + c * SN + (n0 ^ ((c & 7) << 3)));
      }
#pragma unroll
      for (int dt = 0; dt < 4; ++dt) {
        const int d = dh * 64 + dt * 16 + li;
        bb[dt] = *reinterpret_cast<const short8*>(eks + d * SN + (n0 ^ ((d & 7) << 3)));
      }
#pragma unroll
      for (int am = 0; am < 2; ++am)
#pragma unroll
        for (int dt = 0; dt < 4; ++dt)
          acc[am][dt] = __builtin_amdgcn_mfma_f32_16x16x32_bf16(a[am], bb[dt], acc[am][dt], 0, 0, 0);
    }
    asm volatile("s_waitcnt lgkmcnt(0)" ::: "memory");
    __builtin_amdgcn_s_barrier();
    __builtin_amdgcn_sched_barrier(0);
  }

  // ---- epilogue: part + zpart (deterministic, no atomics) ----
  float* P = part + ((size_t)kc * B_ + b) * C_ * C_;
#pragma unroll
  for (int am = 0; am < 2; ++am)
#pragma unroll
    for (int dt = 0; dt < 4; ++dt)
#pragma unroll
      for (int r = 0; r < 4; ++r) {
        const int c = cg * 32 + am * 16 + lg * 4 + r;
        const int d = dh * 64 + dt * 16 + li;
        P[c * C_ + d] = acc[am][dt][r];
      }
  if (mat == 0) {
#pragma unroll
    for (int dt = 0; dt < 2; ++dt) {
      float z = zac[dt];
      z += __shfl_xor(z, 16);
      z += __shfl_xor(z, 32);
      if (lg == 0)
        zpart[((size_t)kc * B_ + b) * C_ + dblk * 32 + dt * 16 + li] = z;
    }
  }
}

// ---------------------------------------------------------------------------
// KB2: cs = (sum_kc part)/Z ; M = cs·qw (bf16), T = cs·qb
// (unchanged from rounds 8/9/10)
// ---------------------------------------------------------------------------
__global__ __launch_bounds__(256) void kb2_fin(
    const float* __restrict__ part, const float* __restrict__ zpart,
    const float* __restrict__ qw, const float* __restrict__ qb,
    u16* __restrict__ M, float* __restrict__ T) {
  const int b = blockIdx.y;
  const int cs0 = blockIdx.x * 16;
  const int tid = threadIdx.x;
  __shared__ float cs[16][128];
  __shared__ float Zs[128];
  if (tid < 128) {
    float s = 0.f;
    for (int kc = 0; kc < NC; ++kc)
      s += zpart[((size_t)kc * B_ + b) * C_ + tid];
    Zs[tid] = s;
  }
  __syncthreads();
#pragma unroll
  for (int i = 0; i < 8; ++i) {
    const int e = tid + i * 256;
    const int cl = e >> 7, d = e & 127;
    float s = 0.f;
    for (int kc = 0; kc < NC; ++kc)
      s += part[(((size_t)kc * B_ + b) * C_ + (cs0 + cl)) * C_ + d];
    cs[cl][d] = s / Zs[d];
  }
  __syncthreads();
  const int cl = tid >> 4, e0 = (tid & 15) * 8;
  float m[8] = {};
  for (int d = 0; d < 128; ++d) {
    const float cv = cs[cl][d];
    const float* qr = qw + d * C_ + e0;
#pragma unroll
    for (int j = 0; j < 8; ++j) m[j] += cv * qr[j];
  }
  u16* mp = M + ((size_t)b * C_ + cs0 + cl) * C_ + e0;
#pragma unroll
  for (int j = 0; j < 8; ++j) mp[j] = (u16)f2bf(m[j]);
  if (tid < 16) {
    float tv = 0.f;
    for (int d = 0; d < 128; ++d) tv += cs[tid][d] * qb[d];
    T[b * C_ + cs0 + tid] = tv;
  }
}

// ---------------------------------------------------------------------------
// K4: out = M·q_feat + T (fp32).  grid (N/128, B) = 1024 blocks, 256 thr.
// Software-pipelined 2-tile blocks (KA pattern): tile-1 global loads are
// issued BEFORE the first raw s_barrier (lgkmcnt-only wait — no vmcnt
// drain), so they fly under tile-0's MFMA + stores.  Double-buffered qt.
// Staging/MFMA/stores per tile are the round-9 proven forms (identical
// arithmetic and store values; only scheduling changed).
// ---------------------------------------------------------------------------
#define K4_LOADS(DST_, NOFF_) do {                                           \
  _Pragma("unroll") for (int j_ = 0; j_ < 32; ++j_)                          \
    DST_[j_] = qb[(size_t)(w * 32 + j_) * N_ + (NOFF_) + lane];              \
} while (0)

#define K4_XWRITE(BUF_, SRC_) do {                                           \
  _Pragma("unroll") for (int o_ = 0; o_ < 4; ++o_) {                         \
    uint4 v_;                                                                \
    v_.x = cvtpk(SRC_[o_ * 8 + 0], SRC_[o_ * 8 + 1]);                        \
    v_.y = cvtpk(SRC_[o_ * 8 + 2], SRC_[o_ * 8 + 3]);                        \
    v_.z = cvtpk(SRC_[o_ * 8 + 4], SRC_[o_ * 8 + 5]);                        \
    v_.w = cvtpk(SRC_[o_ * 8 + 6], SRC_[o_ * 8 + 7]);                        \
    *reinterpret_cast<uint4*>(                                               \
        (BUF_) + lane * C_ + ((w * 32 + o_ * 8) ^ ((lane & 7) << 3))) = v_;  \
  }                                                                          \
} while (0)

#define K4_MFMA_STORE(BUF_, NOFF_) do {                                      \
  f32x4 acc_[2][4] = {};                                                     \
  _Pragma("unroll") for (int nt_ = 0; nt_ < 4; ++nt_) {                      \
    const int n_ = nt_ * 16 + li;                                            \
    _Pragma("unroll") for (int ks_ = 0; ks_ < 4; ++ks_) {                    \
      short8 bb_ = *reinterpret_cast<const short8*>(                         \
          (BUF_) + n_ * C_ + ((ks_ * 32 + lg * 8) ^ ((n_ & 7) << 3)));       \
      _Pragma("unroll") for (int ct_ = 0; ct_ < 2; ++ct_)                    \
        acc_[ct_][nt_] = __builtin_amdgcn_mfma_f32_16x16x32_bf16(            \
            mreg[ct_][ks_], bb_, acc_[ct_][nt_], 0, 0, 0);                   \
    }                                                                        \
  }                                                                          \
  _Pragma("unroll") for (int ct_ = 0; ct_ < 2; ++ct_)                        \
  _Pragma("unroll") for (int r_ = 0; r_ < 4; ++r_) {                         \
    const int c_ = w * 32 + ct_ * 16 + lg * 4 + r_;                          \
    float* op_ = out + ((size_t)b * C_ + c_) * N_ + nb + (NOFF_);            \
    const float t_ = tcv[ct_][r_];                                           \
    _Pragma("unroll") for (int nt_ = 0; nt_ < 4; ++nt_)                      \
      op_[nt_ * 16 + li] = acc_[ct_][nt_][r_] + t_;                          \
  }                                                                          \
} while (0)

__global__ __launch_bounds__(256) void k4_out(const u16* __restrict__ M,
                                              const float* __restrict__ T,
                                              const float* __restrict__ q,
                                              float* __restrict__ out) {
  __shared__ u16 qt[2][SN4 * C_];  // double-buffered [n][d] bf16, 2 x 16 KB
  const int b = blockIdx.y;
  const int nb = blockIdx.x * 128;   // block covers 128 n = 2 subtiles
  const int tid = threadIdx.x;
  const int w = tid >> 6, lane = tid & 63;
  const int lg = lane >> 4, li = lane & 15;

  const float* qb = q + (size_t)b * C_ * N_ + nb;

  // M fragments (A operand, rows c) + T per output row (L2-hot)
  short8 mreg[2][4];
  const u16* Mb = M + (size_t)b * C_ * C_;
#pragma unroll
  for (int ct = 0; ct < 2; ++ct)
#pragma unroll
    for (int ks = 0; ks < 4; ++ks)
      mreg[ct][ks] = *reinterpret_cast<const short8*>(
          Mb + (w * 32 + ct * 16 + li) * C_ + ks * 32 + lg * 8);
  float tcv[2][4];
#pragma unroll
  for (int ct = 0; ct < 2; ++ct)
#pragma unroll
    for (int r = 0; r < 4; ++r)
      tcv[ct][r] = T[b * C_ + w * 32 + ct * 16 + lg * 4 + r];

  // ---- tile 0 stage; issue tile 1 loads BEFORE barrier (stay in flight) ----
  float xr0[32], xr1[32];
  K4_LOADS(xr0, 0);
  K4_XWRITE(&qt[0][0], xr0);
  K4_LOADS(xr1, SN4);
  asm volatile("s_waitcnt lgkmcnt(0)" ::: "memory");
  __builtin_amdgcn_s_barrier();
  __builtin_amdgcn_sched_barrier(0);

  // ---- tile 0 MFMA + store (tile-1 loads in flight underneath) ----
  K4_MFMA_STORE(&qt[0][0], 0);

  // ---- tile 1 pack/write (compiler waits vmcnt for xr1 only) ----
  K4_XWRITE(&qt[1][0], xr1);
  asm volatile("s_waitcnt lgkmcnt(0)" ::: "memory");
  __builtin_amdgcn_s_barrier();
  __builtin_amdgcn_sched_barrier(0);

  // ---- tile 1 MFMA + store ----
  K4_MFMA_STORE(&qt[1][0], SN4);
}

// ---------------------------------------------------------------------------
extern "C" void kernel_launch(void* const* d_in, const int* in_sizes, int n_in,
                              void* d_out, int out_size, void* d_ws, size_t ws_size,
                              hipStream_t stream) {
  const float* q_feat  = (const float*)d_in[0];
  const float* kv_feat = (const float*)d_in[1];
  const float* q_w = (const float*)d_in[2];
  const float* q_b = (const float*)d_in[3];
  const float* k_w = (const float*)d_in[4];
  const float* k_b = (const float*)d_in[5];
  const float* v_w = (const float*)d_in[6];
  const float* v_b = (const float*)d_in[7];
  float* out = (float*)d_out;

  char* ws = (char*)d_ws;
  const size_t szPart = (size_t)NC * B_ * C_ * C_ * sizeof(float);  // 16 MB
  const size_t szZp   = (size_t)NC * B_ * C_ * sizeof(float);       // 128 KB
  const size_t szWbf  = (size_t)2 * C_ * C_ * sizeof(u16);          // 64 KB
  const size_t szM    = (size_t)B_ * C_ * C_ * sizeof(u16);         // 256 KB

  float* part  = (float*)ws;
  float* zpart = (float*)(ws + szPart);
  u16*   wbf   = (u16*)(ws + szPart + szZp);
  u16*   M     = (u16*)(ws + szPart + szZp + szWbf);
  float* T     = (float*)(ws + szPart + szZp + szWbf + szM);

  k0_wcvt<<<dim3(32), 256, 0, stream>>>(k_w, v_w, wbf);
  ka_projctx<<<dim3(NC, B_), 512, 0, stream>>>(kv_feat, wbf, k_b, v_b, part, zpart);
  kb2_fin<<<dim3(8, B_), 256, 0, stream>>>(part, zpart, q_w, q_b, M, T);
  k4_out<<<dim3(N_ / 128, B_), 256, 0, stream>>>(M, T, q_feat, out);
}

// Round 12
// 73.218 us; speedup vs baseline: 1.0410x; 1.0343x over previous
//
#include <hip/hip_runtime.h>
#include <hip/hip_bf16.h>
#include <cstdint>

#define B_ 8
#define C_ 128
#define N_ 16384   // H*W
#define CHN 512    // n per block (KA and K4)
#define SN 128     // n per subtile
#define NST 4      // subtiles per block
#define NC (N_ / CHN)  // 32 chunks

typedef __attribute__((ext_vector_type(8))) short short8;
typedef __attribute__((ext_vector_type(4))) float f32x4;
typedef __attribute__((ext_vector_type(4))) unsigned short us4;
typedef unsigned short u16;

__device__ __forceinline__ short f2bf(float f) {
  union { float f; unsigned u; } c; c.f = f;
  unsigned r = (c.u + 0x7FFFu + ((c.u >> 16) & 1u)) >> 16;
  return (short)r;
}

__device__ __forceinline__ unsigned cvtpk(float lo, float hi) {
  unsigned r;
  asm("v_cvt_pk_bf16_f32 %0, %1, %2" : "=v"(r) : "v"(lo), "v"(hi));
  return r;
}

union SB { short8 s8; unsigned u[4]; };

// ---------------------------------------------------------------------------
// K0: preconvert k_w, v_w (fp32) -> wbf (bf16 [2][128][128])
// ---------------------------------------------------------------------------
__global__ __launch_bounds__(256) void k0_wcvt(const float* __restrict__ kw,
                                               const float* __restrict__ vw,
                                               u16* __restrict__ wbf) {
  const int g = blockIdx.x * 256 + threadIdx.x;  // 0..8191 float4s
  const int mat = g >> 12, o4 = g & 4095;
  const float* src = mat ? vw : kw;
  float4 f = reinterpret_cast<const float4*>(src)[o4];
  us4 s;
  s[0] = (u16)f2bf(f.x); s[1] = (u16)f2bf(f.y);
  s[2] = (u16)f2bf(f.z); s[3] = (u16)f2bf(f.w);
  reinterpret_cast<us4*>(wbf + (size_t)mat * C_ * C_)[o4] = s;
}

// ---------------------------------------------------------------------------
// KA: fused projection + context partial (rounds 6-11 core, passed 0.03125)
// + NEW chunked XCD remap: XCD k owns batch k (contiguous kv/out regions
// per XCD L2 -> address-ordered evictions -> DRAM row locality).
// ---------------------------------------------------------------------------
#define KA_LOADS(ST_) do {                                                   \
  _Pragma("unroll") for (int h_ = 0; h_ < 2; ++h_)                           \
  _Pragma("unroll") for (int j_ = 0; j_ < 16; ++j_)                          \
    xr[h_][j_] = xw[(size_t)j_ * N_ + (ST_) * SN + h_ * 64 + lane];          \
} while (0)

#define KA_XWRITE(BUF_) do {                                                 \
  _Pragma("unroll") for (int h_ = 0; h_ < 2; ++h_) {                         \
    const int n_ = h_ * 64 + lane;                                           \
    unsigned pk_[8];                                                         \
    _Pragma("unroll") for (int p_ = 0; p_ < 8; ++p_)                         \
      pk_[p_] = cvtpk(xr[h_][2 * p_], xr[h_][2 * p_ + 1]);                   \
    _Pragma("unroll") for (int o_ = 0; o_ < 2; ++o_) {                       \
      uint4 q_;                                                              \
      q_.x = pk_[o_ * 4]; q_.y = pk_[o_ * 4 + 1];                            \
      q_.z = pk_[o_ * 4 + 2]; q_.w = pk_[o_ * 4 + 3];                        \
      *reinterpret_cast<uint4*>(                                             \
          (BUF_) + n_ * SN + ((w * 16 + o_ * 8) ^ ((n_ & 7) << 3))) = q_;    \
    }                                                                        \
  }                                                                          \
} while (0)

__global__ __launch_bounds__(512, 2) void ka_projctx(
    const float* __restrict__ kv, const u16* __restrict__ wbf,
    const float* __restrict__ kb, const float* __restrict__ vb,
    float* __restrict__ part, float* __restrict__ zpart) {
  __shared__ u16 xt[2][C_ * SN];   // 2 x 32 KB transposed bf16 x
  __shared__ u16 eks[C_ * SN];     // 32 KB EK stash [d][n]
  __shared__ u16 vs [C_ * SN];     // 32 KB V  stash [c][n]

  // chunked-bijective XCD remap ([0,256) -> [0,256)): XCD k -> batch k
  const int fid = blockIdx.x + blockIdx.y * NC;
  const int fid2 = (fid & 7) * 32 + (fid >> 3);
  const int b = fid2 >> 5, kc = fid2 & 31;
  const int tid = threadIdx.x;
  const int w = tid >> 6, lane = tid & 63;
  const int lg = lane >> 4, li = lane & 15;
  const int mat = w >> 2, dblk = w & 3;
  const int cg = w >> 1, dh = w & 1;

  const float* xb = kv + (size_t)b * C_ * N_ + (size_t)kc * CHN;
  const float* xw = xb + (size_t)(w * 16) * N_;  // wave's 16 c-rows
  const u16* Wm = wbf + (size_t)mat * C_ * C_;
  const float* biasp = mat ? vb : kb;
  u16* S = mat ? vs : eks;

  short8 wreg[2][4];
#pragma unroll
  for (int dt = 0; dt < 2; ++dt)
#pragma unroll
    for (int ks = 0; ks < 4; ++ks)
      wreg[dt][ks] = *reinterpret_cast<const short8*>(
          Wm + (dblk * 32 + dt * 16 + li) * C_ + ks * 32 + lg * 8);
  float bias2[2];
#pragma unroll
  for (int dt = 0; dt < 2; ++dt) bias2[dt] = biasp[dblk * 32 + dt * 16 + li];

  f32x4 acc[2][4] = {};   // ctx accumulator [am c][dt d]
  float zac[2] = {0.f, 0.f};
  float xr[2][16];        // reg-staged x: [n-half][c-row j]

  KA_LOADS(0);
  KA_XWRITE(&xt[0][0]);
  KA_LOADS(1);
  asm volatile("s_waitcnt lgkmcnt(0)" ::: "memory");
  __builtin_amdgcn_s_barrier();
  __builtin_amdgcn_sched_barrier(0);

#pragma unroll
  for (int st = 0; st < NST; ++st) {
    const u16* xc = &xt[st & 1][0];

    if (st < NST - 1) {
      KA_XWRITE(&xt[(st + 1) & 1][0]);
      if (st < NST - 2) KA_LOADS(st + 2);
    }

    // ---- proj: D[n][d] = xT · W^T, in nt-pairs ----
#pragma unroll
    for (int h2 = 0; h2 < 4; ++h2) {
      f32x4 pacc[2][2] = {};  // [ntl][dt]
#pragma unroll
      for (int ntl = 0; ntl < 2; ++ntl) {
        const int n = (h2 * 2 + ntl) * 16 + li;
#pragma unroll
        for (int ks = 0; ks < 4; ++ks) {
          short8 a = *reinterpret_cast<const short8*>(
              xc + n * SN + ((ks * 32 + lg * 8) ^ ((n & 7) << 3)));
#pragma unroll
          for (int dt = 0; dt < 2; ++dt)
            pacc[ntl][dt] = __builtin_amdgcn_mfma_f32_16x16x32_bf16(
                a, wreg[dt][ks], pacc[ntl][dt], 0, 0, 0);
        }
      }
#pragma unroll
      for (int dt = 0; dt < 2; ++dt) {
        const int d = dblk * 32 + dt * 16 + li;
        const float bias = bias2[dt];
#pragma unroll
        for (int ntl = 0; ntl < 2; ++ntl) {
          float v0 = pacc[ntl][dt][0] + bias;
          float v1 = pacc[ntl][dt][1] + bias;
          float v2 = pacc[ntl][dt][2] + bias;
          float v3 = pacc[ntl][dt][3] + bias;
          if (mat == 0) {
            v0 = __expf(v0); v1 = __expf(v1); v2 = __expf(v2); v3 = __expf(v3);
            zac[dt] += (v0 + v1) + (v2 + v3);
          }
          const int nq = (h2 * 2 + ntl) * 16 + lg * 4;
          uint2 pk; pk.x = cvtpk(v0, v1); pk.y = cvtpk(v2, v3);
          *reinterpret_cast<uint2*>(S + d * SN + (nq ^ ((d & 7) << 3))) = pk;
        }
      }
    }
    asm volatile("s_waitcnt lgkmcnt(0)" ::: "memory");
    __builtin_amdgcn_s_barrier();
    __builtin_amdgcn_sched_barrier(0);

    // ---- ctx: part += V·EK^T over this subtile's 128 n ----
#pragma unroll
    for (int kk = 0; kk < 4; ++kk) {
      const int n0 = kk * 32 + lg * 8;
      short8 a[2], bb[4];
#pragma unroll
      for (int am = 0; am < 2; ++am) {
        const int c = cg * 32 + am * 16 + li;
        a[am] = *reinterpret_cast<const short8*>(vs + c * SN + (n0 ^ ((c & 7) << 3)));
      }
#pragma unroll
      for (int dt = 0; dt < 4; ++dt) {
        const int d = dh * 64 + dt * 16 + li;
        bb[dt] = *reinterpret_cast<const short8*>(eks + d * SN + (n0 ^ ((d & 7) << 3)));
      }
#pragma unroll
      for (int am = 0; am < 2; ++am)
#pragma unroll
        for (int dt = 0; dt < 4; ++dt)
          acc[am][dt] = __builtin_amdgcn_mfma_f32_16x16x32_bf16(a[am], bb[dt], acc[am][dt], 0, 0, 0);
    }
    asm volatile("s_waitcnt lgkmcnt(0)" ::: "memory");
    __builtin_amdgcn_s_barrier();
    __builtin_amdgcn_sched_barrier(0);
  }

  // ---- epilogue: part + zpart (deterministic, no atomics) ----
  float* P = part + ((size_t)kc * B_ + b) * C_ * C_;
#pragma unroll
  for (int am = 0; am < 2; ++am)
#pragma unroll
    for (int dt = 0; dt < 4; ++dt)
#pragma unroll
      for (int r = 0; r < 4; ++r) {
        const int c = cg * 32 + am * 16 + lg * 4 + r;
        const int d = dh * 64 + dt * 16 + li;
        P[c * C_ + d] = acc[am][dt][r];
      }
  if (mat == 0) {
#pragma unroll
    for (int dt = 0; dt < 2; ++dt) {
      float z = zac[dt];
      z += __shfl_xor(z, 16);
      z += __shfl_xor(z, 32);
      if (lg == 0)
        zpart[((size_t)kc * B_ + b) * C_ + dblk * 32 + dt * 16 + li] = z;
    }
  }
}

// ---------------------------------------------------------------------------
// KB2: cs = (sum_kc part)/Z ; M = cs·qw (bf16), T = cs·qb
// (unchanged from rounds 8-11)
// ---------------------------------------------------------------------------
__global__ __launch_bounds__(256) void kb2_fin(
    const float* __restrict__ part, const float* __restrict__ zpart,
    const float* __restrict__ qw, const float* __restrict__ qb,
    u16* __restrict__ M, float* __restrict__ T) {
  const int b = blockIdx.y;
  const int cs0 = blockIdx.x * 16;
  const int tid = threadIdx.x;
  __shared__ float cs[16][128];
  __shared__ float Zs[128];
  if (tid < 128) {
    float s = 0.f;
    for (int kc = 0; kc < NC; ++kc)
      s += zpart[((size_t)kc * B_ + b) * C_ + tid];
    Zs[tid] = s;
  }
  __syncthreads();
#pragma unroll
  for (int i = 0; i < 8; ++i) {
    const int e = tid + i * 256;
    const int cl = e >> 7, d = e & 127;
    float s = 0.f;
    for (int kc = 0; kc < NC; ++kc)
      s += part[(((size_t)kc * B_ + b) * C_ + (cs0 + cl)) * C_ + d];
    cs[cl][d] = s / Zs[d];
  }
  __syncthreads();
  const int cl = tid >> 4, e0 = (tid & 15) * 8;
  float m[8] = {};
  for (int d = 0; d < 128; ++d) {
    const float cv = cs[cl][d];
    const float* qr = qw + d * C_ + e0;
#pragma unroll
    for (int j = 0; j < 8; ++j) m[j] += cv * qr[j];
  }
  u16* mp = M + ((size_t)b * C_ + cs0 + cl) * C_ + e0;
#pragma unroll
  for (int j = 0; j < 8; ++j) mp[j] = (u16)f2bf(m[j]);
  if (tid < 16) {
    float tv = 0.f;
    for (int d = 0; d < 128; ++d) tv += cs[tid][d] * qb[d];
    T[b * C_ + cs0 + tid] = tv;
  }
}

// ---------------------------------------------------------------------------
// K4: out = M·q_feat + T (fp32).  grid (32, B) = 256 blocks (1/CU), 512 thr
// = 8 waves, KA-clone 4-subtile pipeline.  Each block covers 512 n -> 2 KB
// contiguous per out-row (vs 512 B) + chunked XCD remap (XCD k = batch k):
// per-XCD L2 aggregates one contiguous 8 MB region -> DRAM row locality.
// Staging wave w owns 16 d-rows; MFMA wave w owns 16 c-rows x 128 n.
// Stores fly async (lgkm-only barriers, vmcnt never drained in-loop).
// ---------------------------------------------------------------------------
#define K4_LOADS(ST_) do {                                                   \
  _Pragma("unroll") for (int h_ = 0; h_ < 2; ++h_)                           \
  _Pragma("unroll") for (int j_ = 0; j_ < 16; ++j_)                          \
    xr[h_][j_] = qw_[(size_t)j_ * N_ + (ST_) * SN + h_ * 64 + lane];         \
} while (0)

#define K4_XWRITE(BUF_) do {                                                 \
  _Pragma("unroll") for (int h_ = 0; h_ < 2; ++h_) {                         \
    const int n_ = h_ * 64 + lane;                                           \
    unsigned pk_[8];                                                         \
    _Pragma("unroll") for (int p_ = 0; p_ < 8; ++p_)                         \
      pk_[p_] = cvtpk(xr[h_][2 * p_], xr[h_][2 * p_ + 1]);                   \
    _Pragma("unroll") for (int o_ = 0; o_ < 2; ++o_) {                       \
      uint4 q_;                                                              \
      q_.x = pk_[o_ * 4]; q_.y = pk_[o_ * 4 + 1];                            \
      q_.z = pk_[o_ * 4 + 2]; q_.w = pk_[o_ * 4 + 3];                        \
      *reinterpret_cast<uint4*>(                                             \
          (BUF_) + n_ * SN + ((w * 16 + o_ * 8) ^ ((n_ & 7) << 3))) = q_;    \
    }                                                                        \
  }                                                                          \
} while (0)

__global__ __launch_bounds__(512) void k4_out(const u16* __restrict__ M,
                                              const float* __restrict__ T,
                                              const float* __restrict__ q,
                                              float* __restrict__ out) {
  __shared__ u16 qt[2][SN * C_];  // double-buffered [n][d] bf16, 2 x 32 KB

  const int fid = blockIdx.x + blockIdx.y * NC;
  const int fid2 = (fid & 7) * 32 + (fid >> 3);  // XCD k -> batch k
  const int b = fid2 >> 5, kc = fid2 & 31;
  const int nb = kc * CHN;
  const int tid = threadIdx.x;
  const int w = tid >> 6, lane = tid & 63;
  const int lg = lane >> 4, li = lane & 15;

  const float* qw_ = q + (size_t)b * C_ * N_ + nb + (size_t)(w * 16) * N_;

  // M fragments (A operand rows c = w*16+li) + T (rows c = w*16+lg*4+r)
  short8 mreg[4];
  const u16* Mb = M + (size_t)b * C_ * C_;
#pragma unroll
  for (int ks = 0; ks < 4; ++ks)
    mreg[ks] = *reinterpret_cast<const short8*>(
        Mb + (w * 16 + li) * C_ + ks * 32 + lg * 8);
  float tcv[4];
#pragma unroll
  for (int r = 0; r < 4; ++r) tcv[r] = T[b * C_ + w * 16 + lg * 4 + r];

  float xr[2][16];  // reg-staged q: [n-half][d-row j]

  K4_LOADS(0);
  K4_XWRITE(&qt[0][0]);
  K4_LOADS(1);
  asm volatile("s_waitcnt lgkmcnt(0)" ::: "memory");
  __builtin_amdgcn_s_barrier();
  __builtin_amdgcn_sched_barrier(0);

#pragma unroll
  for (int st = 0; st < NST; ++st) {
    const u16* xc = &qt[st & 1][0];

    if (st < NST - 1) {
      K4_XWRITE(&qt[(st + 1) & 1][0]);
      if (st < NST - 2) K4_LOADS(st + 2);
    }

    // ---- MFMA: D[c][n]; wave w owns c in [w*16, w*16+16), n in [0,128) ----
    f32x4 acc[8] = {};
#pragma unroll
    for (int nt = 0; nt < 8; ++nt) {
      const int n = nt * 16 + li;
#pragma unroll
      for (int ks = 0; ks < 4; ++ks) {
        short8 bb = *reinterpret_cast<const short8*>(
            xc + n * SN + ((ks * 32 + lg * 8) ^ ((n & 7) << 3)));
        acc[nt] = __builtin_amdgcn_mfma_f32_16x16x32_bf16(
            mreg[ks], bb, acc[nt], 0, 0, 0);
      }
    }

    // ---- stores (async across lgkm-only barrier) ----
#pragma unroll
    for (int r = 0; r < 4; ++r) {
      const int c = w * 16 + lg * 4 + r;
      float* op = out + ((size_t)b * C_ + c) * N_ + nb + st * SN;
      const float t = tcv[r];
#pragma unroll
      for (int nt = 0; nt < 8; ++nt)
        op[nt * 16 + li] = acc[nt][r] + t;
    }

    asm volatile("s_waitcnt lgkmcnt(0)" ::: "memory");
    __builtin_amdgcn_s_barrier();
    __builtin_amdgcn_sched_barrier(0);
  }
}

// ---------------------------------------------------------------------------
extern "C" void kernel_launch(void* const* d_in, const int* in_sizes, int n_in,
                              void* d_out, int out_size, void* d_ws, size_t ws_size,
                              hipStream_t stream) {
  const float* q_feat  = (const float*)d_in[0];
  const float* kv_feat = (const float*)d_in[1];
  const float* q_w = (const float*)d_in[2];
  const float* q_b = (const float*)d_in[3];
  const float* k_w = (const float*)d_in[4];
  const float* k_b = (const float*)d_in[5];
  const float* v_w = (const float*)d_in[6];
  const float* v_b = (const float*)d_in[7];
  float* out = (float*)d_out;

  char* ws = (char*)d_ws;
  const size_t szPart = (size_t)NC * B_ * C_ * C_ * sizeof(float);  // 16 MB
  const size_t szZp   = (size_t)NC * B_ * C_ * sizeof(float);       // 128 KB
  const size_t szWbf  = (size_t)2 * C_ * C_ * sizeof(u16);          // 64 KB
  const size_t szM    = (size_t)B_ * C_ * C_ * sizeof(u16);         // 256 KB

  float* part  = (float*)ws;
  float* zpart = (float*)(ws + szPart);
  u16*   wbf   = (u16*)(ws + szPart + szZp);
  u16*   M     = (u16*)(ws + szPart + szZp + szWbf);
  float* T     = (float*)(ws + szPart + szZp + szWbf + szM);

  k0_wcvt<<<dim3(32), 256, 0, stream>>>(k_w, v_w, wbf);
  ka_projctx<<<dim3(NC, B_), 512, 0, stream>>>(kv_feat, wbf, k_b, v_b, part, zpart);
  kb2_fin<<<dim3(8, B_), 256, 0, stream>>>(part, zpart, q_w, q_b, M, T);
  k4_out<<<dim3(NC, B_), 512, 0, stream>>>(M, T, q_feat, out);
}